// Round 9
// baseline (154.138 us; speedup 1.0000x reference)
//
#include <hip/hip_runtime.h>

#define NR 131072
#define DD 32
#define KK 64
#define BETA_C 10.0f
#define NB1 2048    // phase1 blocks (64 rows each)
#define WROWS 256   // rows per syrk worker
#define GRIDW 640   // >= sum ceil(c_k/WROWS) <= 512+64 = 576
#define TRI(i, j) ((i) * ((i) + 1) / 2 + (j))

// ---------------------------------------------------------------------------
// ws layout (float-indexed), ws_size = 256 MiB:
//   [0,64)          hist_g (int, planner out)
//   [64,65)         lossAcc                      (memset)
//   [128,33920)     m2low_g (K x 528 tri)        (memset)
//   [33920,35968)   sums_g (K x 32)              (memset)
//   [35968,36033)   segStart (int 65)
//   [36096,36160)   cursor (int 64)
//   [36160,36320)   wk (uchar GRIDW)
//   [36320,36960)   wbase (int GRIDW)
//   [36960,37600)   wcnt (int GRIDW)
//   [37632,70400)   pred8 (uchar N)
//   [70400,201472)  fillPart (float [K][NB1], fully overwritten)
//   [201472,332544) histPart (int [K][NB1], fully overwritten)
//   [332544,...)    xsort (N*D floats, fully overwritten)
// memset zeroes only [64,35968).
// ---------------------------------------------------------------------------

// phase 1 v5: 4-way k-split. Block = 64 rows x 4 waves; wave h owns clusters
// [16h,16h+16) (wave-uniform -> s_load/K$ path). d2 per (row,k) computed with
// the exact R8 expression/order (bit-identical assignments). 4-way
// online-softmax + lexicographic argmin merge through LDS. Filling via
// 17-shuffle transpose-reduce; fill/hist flushed as per-block partials
// (plain stores, no global atomics).
__global__ __launch_bounds__(256) void phase1_kernel(
    const float* __restrict__ x, const float* __restrict__ centers,
    float* __restrict__ fillPart, int* __restrict__ histPart,
    unsigned char* __restrict__ pred_g) {
  __shared__ float cnS[KK];
  __shared__ float bestA[4][64];
  __shared__ float ssumA[4][64];
  __shared__ int biA[4][64];
  __shared__ int histS[KK];

  const int tid = threadIdx.x;
  const int lane = tid & 63;
  const int h = tid >> 6;  // k-group 0..3
  const int hU = __builtin_amdgcn_readfirstlane(h);
  const int b = blockIdx.x;
  const int row = b * 64 + lane;

  if (tid < KK) {
    float s = 0.f;
    const float* cp = centers + tid * DD;
#pragma unroll
    for (int j = 0; j < DD; ++j) s += cp[j] * cp[j];
    cnS[tid] = s;
    histS[tid] = 0;
  }
  __syncthreads();

  float xr[DD];  // row in VGPRs (4 waves load the same 8 KB tile -> L1 hits)
  const float4* xp = (const float4*)(x + (size_t)row * DD);
#pragma unroll
  for (int j = 0; j < 8; ++j) {
    const float4 v = xp[j];
    xr[4 * j + 0] = v.x;
    xr[4 * j + 1] = v.y;
    xr[4 * j + 2] = v.z;
    xr[4 * j + 3] = v.w;
  }
  float xx = 0.f;
#pragma unroll
  for (int j = 0; j < DD; ++j) xx += xr[j] * xr[j];

  const float* cb = centers + hU * 16 * DD;  // uniform base -> s_load
  float pv[16];
  float best = 3.4e38f;
  int bi = 0;
#pragma unroll
  for (int kk = 0; kk < 16; ++kk) {
    float dot = 0.f;
#pragma unroll
    for (int j = 0; j < DD; ++j) dot += xr[j] * cb[kk * DD + j];
    const float d2 = xx - 2.0f * dot + cnS[hU * 16 + kk];  // == R8 bitwise
    pv[kk] = d2;
    if (d2 < best) { best = d2; bi = hU * 16 + kk; }  // first-index ties
  }

  float ssum = 0.f;
#pragma unroll
  for (int kk = 0; kk < 16; ++kk) {
    const float e = __expf(BETA_C * (best - pv[kk]));  // arg <= 0
    pv[kk] = e;
    ssum += e;
  }

  // 4-way merge: global best/argmin (ascending h + strict < == first-index
  // tie-break over ascending k), online-softmax normalizer.
  bestA[h][lane] = best;
  ssumA[h][lane] = ssum;
  biA[h][lane] = bi;
  __syncthreads();
  float B = bestA[0][lane];
  int BI = biA[0][lane];
#pragma unroll
  for (int q = 1; q < 4; ++q) {
    const float bq = bestA[q][lane];
    if (bq < B) { B = bq; BI = biA[q][lane]; }
  }
  float Z = 0.f;
#pragma unroll
  for (int q = 0; q < 4; ++q)
    Z += ssumA[q][lane] * __expf(BETA_C * (B - bestA[q][lane]));
  const float scale = __expf(BETA_C * (B - best)) / Z;
#pragma unroll
  for (int kk = 0; kk < 16; ++kk) pv[kk] *= scale;

  if (h == 0) {
    pred_g[row] = (unsigned char)BI;
    atomicAdd(&histS[BI], 1);
  }

  // transpose-reduce 16 values over 64 lanes: stages 8,4,2,1 leave lane l
  // holding its quarter's sum of p[l&15]; xor16+xor32 fold the 4 quarters.
#pragma unroll
  for (int m = 8; m >= 1; m >>= 1) {
    const bool hi_ = (lane & m) != 0;
#pragma unroll
    for (int i = 0; i < m; ++i) {
      const float send = hi_ ? pv[i] : pv[i + m];
      const float recv = __shfl_xor(send, m, 64);
      const float keep = hi_ ? pv[i + m] : pv[i];
      pv[i] = keep + recv;
    }
  }
  float v = pv[0];
  v += __shfl_xor(v, 16, 64);
  v += __shfl_xor(v, 32, 64);
  if (lane < 16) fillPart[(size_t)(hU * 16 + lane) * NB1 + b] = v;

  __syncthreads();
  if (tid < KK) histPart[(size_t)tid * NB1 + b] = histS[tid];
}

// planner v3: fold histPart (K x NB1) -> counts, then wave-scan -> segStart/
// cursor + worker table. 256 threads: 4 threads per cluster for the fold.
__global__ __launch_bounds__(256) void planner_kernel(
    const int* __restrict__ histPart, int* __restrict__ hist_g,
    int* __restrict__ segStart, int* __restrict__ cursor,
    unsigned char* __restrict__ wk, int* __restrict__ wbase,
    int* __restrict__ wcnt) {
  __shared__ int part[256];
  __shared__ int cntS[KK];
  const int t = threadIdx.x;
  const int k = t >> 2, q = t & 3;
  const int4* hp = (const int4*)(histPart + (size_t)k * NB1 + q * (NB1 / 4));
  int s = 0;
#pragma unroll 4
  for (int i = 0; i < NB1 / 16; ++i) {
    const int4 v = hp[i];
    s += v.x + v.y + v.z + v.w;
  }
  part[t] = s;
  __syncthreads();
  if (q == 0) cntS[k] = part[t] + part[t + 1] + part[t + 2] + part[t + 3];
  __syncthreads();
  if (t < KK) {  // single wave
    const int c = cntS[t];
    hist_g[t] = c;
    int inc = c;
#pragma unroll
    for (int off = 1; off < 64; off <<= 1) {
      const int v2 = __shfl_up(inc, off, 64);
      if (t >= off) inc += v2;
    }
    const int seg = inc - c;
    segStart[t] = seg;
    cursor[t] = seg;
    if (t == 63) segStart[KK] = inc;

    const int nw = (c + WROWS - 1) / WROWS;
    int winc = nw;
#pragma unroll
    for (int off = 1; off < 64; off <<= 1) {
      const int v2 = __shfl_up(winc, off, 64);
      if (t >= off) winc += v2;
    }
    const int woff = winc - nw;
    const int wtot = __shfl(winc, 63, 64);
    for (int wi = 0; wi < nw; ++wi) {
      wk[woff + wi] = (unsigned char)t;
      wbase[woff + wi] = seg + wi * WROWS;
      wcnt[woff + wi] = min(WROWS, c - wi * WROWS);
    }
    for (int w = wtot + t; w < GRIDW; w += 64) wk[w] = 255;
  }
}

// scatter (R8 verbatim, validated): counting-sort x into xsort.
__global__ __launch_bounds__(256) void scatter_kernel(
    const float* __restrict__ x, const unsigned char* __restrict__ pred_g,
    int* __restrict__ cursor, float* __restrict__ xsort) {
  __shared__ int histS[KK];
  __shared__ int baseS[KK];
  __shared__ int slotS[256];

  const int tid = threadIdx.x;
  if (tid < KK) histS[tid] = 0;
  __syncthreads();

  const int row = blockIdx.x * 256 + tid;
  const int bi = pred_g[row];
  const int rank = atomicAdd(&histS[bi], 1);
  __syncthreads();
  if (tid < KK) {
    const int hh = histS[tid];
    baseS[tid] = hh ? atomicAdd(&cursor[tid], hh) : 0;
  }
  __syncthreads();
  slotS[tid] = baseS[bi] + rank;
  __syncthreads();

  const float4* xin = (const float4*)x + (size_t)blockIdx.x * 2048;
  float4* xo = (float4*)xsort;
#pragma unroll
  for (int j = 0; j < 8; ++j) {
    const int f = tid + 256 * j;
    const int rl = f >> 3;
    const int pt = f & 7;
    xo[(size_t)slotS[rl] * 8 + pt] = xin[f];  // reads perfectly coalesced
  }
}

// syrk (R8 verbatim, validated).
__global__ __launch_bounds__(256) void syrk_kernel(
    const float* __restrict__ xsort, const unsigned char* __restrict__ wk,
    const int* __restrict__ wbase, const int* __restrict__ wcnt,
    float* __restrict__ m2low_g, float* __restrict__ sums_g) {
  __shared__ float xsT[DD][68];

  const int b = blockIdx.x;
  const int k = wk[b];
  if (k == 255) return;
  const int tid = threadIdx.x;
  const int base = wbase[b];
  const int total = wcnt[b];

  const int ti = tid >> 4, tj = tid & 15;
  const int i0 = ti, i1 = ti + 16, j0 = tj, j1 = tj + 16;
  float c00 = 0.f, c10 = 0.f, c11 = 0.f, sd0 = 0.f, sd1 = 0.f;

  for (int off = 0; off < total; off += 64) {
    const int cnt = min(64, total - off);
    const int cnt4 = (cnt + 3) & ~3;
    __syncthreads();
    const float* src = xsort + (size_t)(base + off) * DD;
    for (int e = tid; e < cnt * DD; e += 256)
      xsT[e & 31][e >> 5] = src[e];  // fully coalesced
    for (int e = cnt * DD + tid; e < cnt4 * DD; e += 256)
      xsT[e & 31][e >> 5] = 0.f;
    __syncthreads();
    for (int g = 0; g < (cnt4 >> 2); ++g) {
      const float4 A0 = *(const float4*)&xsT[i0][4 * g];
      const float4 A1 = *(const float4*)&xsT[i1][4 * g];
      const float4 B0 = *(const float4*)&xsT[j0][4 * g];
      const float4 B1 = *(const float4*)&xsT[j1][4 * g];
      c00 += A0.x * B0.x + A0.y * B0.y + A0.z * B0.z + A0.w * B0.w;
      c10 += A1.x * B0.x + A1.y * B0.y + A1.z * B0.z + A1.w * B0.w;
      c11 += A1.x * B1.x + A1.y * B1.y + A1.z * B1.z + A1.w * B1.w;
      if (tj == 0) {
        sd0 += A0.x + A0.y + A0.z + A0.w;
        sd1 += A1.x + A1.y + A1.z + A1.w;
      }
    }
  }

  float* m2k = m2low_g + k * 528;
  atomicAdd(&m2k[TRI(i1, j0)], c10);
  if (tj <= ti) {
    atomicAdd(&m2k[TRI(i0, j0)], c00);
    atomicAdd(&m2k[TRI(i1, j1)], c11);
  }
  if (tj == 0) {
    atomicAdd(&sums_g[k * DD + i0], sd0);
    atomicAdd(&sums_g[k * DD + i1], sd1);
  }
}

// finalize A: one block per cluster; folds fillPart + mean/cov loss terms.
__global__ __launch_bounds__(256) void finalizeA_kernel(
    const float* __restrict__ fillPart, const int* __restrict__ hist_g,
    const float* __restrict__ sums_g, const float* __restrict__ m2low_g,
    const float* __restrict__ ft, const float* __restrict__ mt,
    const float* __restrict__ ct, float* __restrict__ lossAcc) {
  __shared__ float meanS[DD];
  __shared__ float wred[4];
  __shared__ float wred2[4];
  const int t = threadIdx.x;
  const int k = blockIdx.x;

  const float inv = 1.0f / fmaxf((float)hist_g[k], 1.0f);
  if (t < DD) meanS[t] = sums_g[k * DD + t] * inv;

  float fs = 0.f;
  for (int i = t; i < NB1; i += 256) fs += fillPart[(size_t)k * NB1 + i];
  fs += __shfl_xor(fs, 32, 64);
  fs += __shfl_xor(fs, 16, 64);
  fs += __shfl_xor(fs, 8, 64);
  fs += __shfl_xor(fs, 4, 64);
  fs += __shfl_xor(fs, 2, 64);
  fs += __shfl_xor(fs, 1, 64);
  if ((t & 63) == 0) wred2[t >> 6] = fs;
  __syncthreads();  // covers meanS + wred2

  float acc = 0.f;
  if (t < DD) {
    const float d = meanS[t] - mt[k * DD + t];
    acc += d * d * (1.0f / (KK * DD));
  }
  if (t == 0) {
    const float S = wred2[0] + wred2[1] + wred2[2] + wred2[3];
    const float f = S * (1.0f / (float)NR) - ft[k];
    acc += f * f * (1.0f / KK);
  }
  const float* m2k = m2low_g + k * 528;
  const float* ctk = ct + k * (DD * DD);
#pragma unroll
  for (int u = 0; u < 4; ++u) {
    const int e = t + 256 * u;
    const int i = e >> 5, j = e & 31;
    const int idx = (i >= j) ? TRI(i, j) : TRI(j, i);
    const float cov = m2k[idx] * inv - meanS[i] * meanS[j];
    const float d = cov - ctk[e];
    acc += d * d * (1.0f / (KK * DD * DD));
  }

  acc += __shfl_xor(acc, 32, 64);
  acc += __shfl_xor(acc, 16, 64);
  acc += __shfl_xor(acc, 8, 64);
  acc += __shfl_xor(acc, 4, 64);
  acc += __shfl_xor(acc, 2, 64);
  acc += __shfl_xor(acc, 1, 64);
  if ((t & 63) == 0) wred[t >> 6] = acc;
  __syncthreads();
  if (t == 0) atomicAdd(lossAcc, wred[0] + wred[1] + wred[2] + wred[3]);
}

__global__ void finalizeB_kernel(const float* __restrict__ lossAcc,
                                 float* __restrict__ out) {
  if (threadIdx.x == 0) out[0] = lossAcc[0];
}

extern "C" void kernel_launch(void* const* d_in, const int* in_sizes, int n_in,
                              void* d_out, int out_size, void* d_ws,
                              size_t ws_size, hipStream_t stream) {
  (void)in_sizes; (void)n_in; (void)out_size; (void)ws_size;
  const float* x = (const float*)d_in[0];
  const float* centers = (const float*)d_in[1];
  const float* ft = (const float*)d_in[2];
  const float* mt = (const float*)d_in[3];
  const float* ct = (const float*)d_in[4];
  float* out = (float*)d_out;

  float* ws = (float*)d_ws;
  int* hist_g = (int*)ws;                                // 64
  float* lossAcc = ws + 64;                              // 1
  float* m2low_g = ws + 128;                             // 33792
  float* sums_g = ws + 33920;                            // 2048
  int* segStart = (int*)(ws + 35968);                    // 65
  int* cursor = (int*)(ws + 36096);                      // 64
  unsigned char* wk = (unsigned char*)(ws + 36160);      // GRIDW bytes
  int* wbase = (int*)(ws + 36320);                       // GRIDW
  int* wcnt = (int*)(ws + 36960);                        // GRIDW
  unsigned char* pred8 = (unsigned char*)(ws + 37632);   // N bytes
  float* fillPart = ws + 70400;                          // K*NB1
  int* histPart = (int*)(ws + 201472);                   // K*NB1
  float* xsort = ws + 332544;                            // N*D

  // zero only lossAcc + m2low + sums (everything else fully overwritten)
  hipMemsetAsync(ws + 64, 0, (size_t)(35968 - 64) * sizeof(float), stream);

  phase1_kernel<<<NB1, 256, 0, stream>>>(x, centers, fillPart, histPart,
                                         pred8);
  planner_kernel<<<1, 256, 0, stream>>>(histPart, hist_g, segStart, cursor, wk,
                                        wbase, wcnt);
  scatter_kernel<<<NR / 256, 256, 0, stream>>>(x, pred8, cursor, xsort);
  syrk_kernel<<<GRIDW, 256, 0, stream>>>(xsort, wk, wbase, wcnt, m2low_g,
                                         sums_g);
  finalizeA_kernel<<<KK, 256, 0, stream>>>(fillPart, hist_g, sums_g, m2low_g,
                                           ft, mt, ct, lossAcc);
  finalizeB_kernel<<<1, 64, 0, stream>>>(lossAcc, out);
}